// Round 12
// baseline (1214.884 us; speedup 1.0000x reference)
//
#include <hip/hip_runtime.h>
#include <hip/hip_bf16.h>
#include <hip/hip_fp16.h>

// RGCN 2-layer, basis-decomposed.
// R11 = R8 (verified, 600us) with TNB 16->8: LDS 76KB->38KB => 4 blocks/CU,
// 8 waves/SIMD (was 4). Phase-1 inner loop byte-identical to R8 (depth-2).
// 1 node/wave in phase 1; phase-2 write guards for the half-filled MFMA M.

typedef __attribute__((ext_vector_type(8))) short bf16x8;
typedef __attribute__((ext_vector_type(4))) float f32x4;
typedef unsigned short u16;
typedef __attribute__((ext_vector_type(4))) unsigned short u16x4;

constexpr int TD   = 128;        // feature dim (both layers' input dim)
constexpr int TB   = 8;          // bases
constexpr int TK   = TB * TD;    // 1024
constexpr int TNB  = 8;          // nodes per block (half-filled MFMA M)
constexpr int BLK  = 512;        // 8 waves
constexpr int ZK   = TK + 8;     // ushort stride for z rows (2064 B)
constexpr int XK   = TD + 8;     // ushort stride for x rows

// returns (hi, lo) bf16 pair packed: hi in low 16, lo in high 16
__device__ inline unsigned int splitbf(float v) {
  unsigned int u = __float_as_uint(v);
  unsigned int r = u + 0x7FFF + ((u >> 16) & 1);   // rne to bf16
  unsigned int hb = r >> 16;
  float hv = __uint_as_float(hb << 16);
  float lo = v - hv;
  unsigned int u2 = __float_as_uint(lo);
  unsigned int r2 = u2 + 0x7FFF + ((u2 >> 16) & 1);
  return (hb & 0xFFFFu) | (r2 & 0xFFFF0000u);
}

__device__ inline u16 f2h(float v) { return __half_as_ushort(__float2half(v)); }
__device__ inline float h2f(u16 b) { return __half2float(__ushort_as_half(b)); }

// W[k][o] -> WT_hi/lo[o][k]
__global__ void k_prep(const float* __restrict__ V1, const float* __restrict__ root1,
                       const float* __restrict__ V2, const float* __restrict__ root2,
                       u16* __restrict__ v1th, u16* __restrict__ v1tl,
                       u16* __restrict__ r1th, u16* __restrict__ r1tl,
                       u16* __restrict__ v2th, u16* __restrict__ v2tl,
                       u16* __restrict__ r2th, u16* __restrict__ r2tl) {
  int idx = blockIdx.x * 256 + threadIdx.x;
  if (idx < 128 * 1024) {
    unsigned int p = splitbf(V1[(size_t)(idx & 1023) * 128 + (idx >> 10)]);
    v1th[idx] = (u16)p; v1tl[idx] = (u16)(p >> 16);
  }
  if (idx < 128 * 128) {
    unsigned int p = splitbf(root1[(size_t)(idx & 127) * 128 + (idx >> 7)]);
    r1th[idx] = (u16)p; r1tl[idx] = (u16)(p >> 16);
  }
  if (idx < 32 * 1024) {
    unsigned int p = splitbf(V2[(size_t)(idx & 1023) * 32 + (idx >> 10)]);
    v2th[idx] = (u16)p; v2tl[idx] = (u16)(p >> 16);
  }
  if (idx < 32 * 128) {
    unsigned int p = splitbf(root2[(size_t)(idx & 127) * 32 + (idx >> 7)]);
    r2th[idx] = (u16)p; r2tl[idx] = (u16)(p >> 16);
  }
}

// f32 x -> fp16 xb (message copy), 4 elems/thread
__global__ void k_xcast(const float* __restrict__ x, u16* __restrict__ xb, int n4) {
  int i = blockIdx.x * 256 + threadIdx.x;
  if (i >= n4) return;
  float4 v = reinterpret_cast<const float4*>(x)[i];
  u16x4 o;
  o[0] = f2h(v.x); o[1] = f2h(v.y); o[2] = f2h(v.z); o[3] = f2h(v.w);
  reinterpret_cast<u16x4*>(xb)[i] = o;
}

__global__ void k_hist(const int* __restrict__ ei, const int* __restrict__ et,
                       int* __restrict__ deg, int* __restrict__ cnt2,
                       int E, int N) {
  int e = blockIdx.x * 256 + threadIdx.x;
  if (e >= E) return;
  int d = ei[E + e];
  int r = et[e];
  atomicAdd(&deg[d], 1);
  atomicAdd(&cnt2[r * N + d], 1);
}

__global__ void k_scan(const int* __restrict__ deg, int* __restrict__ off,
                       int* __restrict__ cursor, int n, int total) {
  __shared__ int wsum[16];
  __shared__ int carry_s;
  const int t = threadIdx.x, lane = t & 63, w = t >> 6;
  if (t == 0) carry_s = 0;
  __syncthreads();
  for (int base = 0; base < n; base += 1024) {
    int i = base + t;
    int v = (i < n) ? deg[i] : 0;
    int s = v;
#pragma unroll
    for (int d = 1; d < 64; d <<= 1) {
      int u = __shfl_up(s, d);
      if (lane >= d) s += u;
    }
    if (lane == 63) wsum[w] = s;
    __syncthreads();
    if (w == 0) {
      int ws = (lane < 16) ? wsum[lane] : 0;
#pragma unroll
      for (int d = 1; d < 16; d <<= 1) {
        int u = __shfl_up(ws, d);
        if (lane >= d) ws += u;
      }
      if (lane < 16) wsum[lane] = ws;
    }
    __syncthreads();
    int wbase = (w == 0) ? 0 : wsum[w - 1];
    int carry = carry_s;
    if (i < n) { int ex = carry + wbase + s - v; off[i] = ex; cursor[i] = ex; }
    __syncthreads();
    if (t == 1023) carry_s = carry + wbase + s;
    __syncthreads();
  }
  if (t == 0) off[n] = total;
}

__global__ void k_scatter(const int* __restrict__ ei, const int* __restrict__ et,
                          int* __restrict__ cursor, const int* __restrict__ cnt2,
                          int* __restrict__ packed, float* __restrict__ invc,
                          int E, int N) {
  int e = blockIdx.x * 256 + threadIdx.x;
  if (e >= E) return;
  int s = ei[e], d = ei[E + e], r = et[e];
  int p = atomicAdd(&cursor[d], 1);
  packed[p] = s | (r << 17);
  invc[p] = 1.0f / (float)cnt2[r * N + d];
}

#define MFMA16(A, B, C) __builtin_amdgcn_mfma_f32_16x16x32_bf16((A), (B), (C), 0, 0, 0)

template <int DOUT, bool RELU, bool SOFTMAX, bool INF32, bool OUTH16>
__global__ __launch_bounds__(BLK, 8) void k_layer(
    const float* __restrict__ inf,       // f32 features (layer 1 x-tile)
    const u16* __restrict__ inb,         // fp16 features (gather; layer-2 x-tile)
    const u16* __restrict__ wth, const u16* __restrict__ wtl,    // [DOUT][TK]
    const float* __restrict__ a,
    const u16* __restrict__ rth, const u16* __restrict__ rtl,    // [DOUT][TD]
    const float* __restrict__ bias, const int* __restrict__ off,
    const int* __restrict__ packed, const float* __restrict__ invc,
    void* __restrict__ outv, int Ntot) {
  extern __shared__ char smem[];
  u16* zh = (u16*)smem;                 // [TNB][ZK]
  u16* zl = zh + TNB * ZK;
  u16* xh = zl + TNB * ZK;              // [TNB][XK]
  u16* xl2 = xh + TNB * XK;
  float* ash = (float*)(xl2 + TNB * XK);  // [256] = a[R][B]
  const int t = threadIdx.x;
  const int n0 = blockIdx.x * TNB;

  if (t < 256) ash[t] = a[t];
  // stage x tile as hi/lo (TNB=8 rows, 256 threads)
  if (t < TNB * 32) {
    int row = t >> 5;
    int c4 = (t & 31) * 4;
    int n = n0 + row;
    float4 v = make_float4(0.f, 0.f, 0.f, 0.f);
    if constexpr (INF32) {
      if (n < Ntot) v = *reinterpret_cast<const float4*>(inf + (size_t)n * TD + c4);
    } else {
      if (n < Ntot) {
        u16x4 hv = *reinterpret_cast<const u16x4*>(inb + (size_t)n * TD + c4);
        v = make_float4(h2f(hv[0]), h2f(hv[1]), h2f(hv[2]), h2f(hv[3]));
      }
    }
    unsigned int p0 = splitbf(v.x), p1 = splitbf(v.y), p2 = splitbf(v.z), p3 = splitbf(v.w);
    xh[row * XK + c4]     = (u16)p0; xl2[row * XK + c4]     = (u16)(p0 >> 16);
    xh[row * XK + c4 + 1] = (u16)p1; xl2[row * XK + c4 + 1] = (u16)(p1 >> 16);
    xh[row * XK + c4 + 2] = (u16)p2; xl2[row * XK + c4 + 2] = (u16)(p2 >> 16);
    xh[row * XK + c4 + 3] = (u16)p3; xl2[row * XK + c4 + 3] = (u16)(p3 >> 16);
  }
  __syncthreads();

  // ---- phase 1: half-wave-per-edge fp16 gather, 2-deep ping-pong ----
  // 1 node per wave (TNB == 8 waves count)
  {
    const int wv = t >> 6, lane = t & 63;
    const int hf = lane >> 5, q = lane & 31;
    const int nn = wv;
    {
      int n = n0 + nn;
      float acc[8][4];
#pragma unroll
      for (int b = 0; b < 8; ++b)
#pragma unroll
        for (int j = 0; j < 4; ++j) acc[b][j] = 0.f;

      if (n < Ntot) {
        int e0 = off[n], e1 = off[n + 1];
        int np = (e1 - e0 + 1) >> 1;

        struct Pk { float4 xv, c0, c1; };
        auto ldst = [&](int pe) {
          Pk P;
          int e = e0 + 2 * pe + hf;
          float iv = 0.f; int r = 0;
          u16x4 xr = {0, 0, 0, 0};
          if (e < e1) {
            int pk = packed[e];
            iv = invc[e];
            r = pk >> 17;
            xr = *reinterpret_cast<const u16x4*>(inb + (size_t)(pk & 131071) * TD + q * 4);
          }
          P.xv = make_float4(h2f(xr[0]), h2f(xr[1]), h2f(xr[2]), h2f(xr[3]));
          float4 t0 = *reinterpret_cast<const float4*>(ash + r * 8);
          float4 t1 = *reinterpret_cast<const float4*>(ash + r * 8 + 4);
          P.c0 = make_float4(t0.x * iv, t0.y * iv, t0.z * iv, t0.w * iv);
          P.c1 = make_float4(t1.x * iv, t1.y * iv, t1.z * iv, t1.w * iv);
          return P;
        };
        auto comp = [&](const Pk& P) {
#define ACCB(bi, cc) \
          acc[bi][0] += (cc) * P.xv.x; acc[bi][1] += (cc) * P.xv.y; \
          acc[bi][2] += (cc) * P.xv.z; acc[bi][3] += (cc) * P.xv.w;
          ACCB(0, P.c0.x) ACCB(1, P.c0.y) ACCB(2, P.c0.z) ACCB(3, P.c0.w)
          ACCB(4, P.c1.x) ACCB(5, P.c1.y) ACCB(6, P.c1.z) ACCB(7, P.c1.w)
#undef ACCB
        };

        Pk A, B;
        if (np > 0) A = ldst(0);
        if (np > 1) B = ldst(1);
        for (int pe = 0; pe < np; pe += 2) {
          comp(A);
          if (pe + 2 < np) A = ldst(pe + 2);
          if (pe + 1 < np) {
            comp(B);
            if (pe + 3 < np) B = ldst(pe + 3);
          }
        }
      }

      // cross-half reduce; hf==0 lanes write BOTH hi and lo
#pragma unroll
      for (int b = 0; b < 8; ++b) {
        float v0 = acc[b][0] + __shfl_xor(acc[b][0], 32);
        float v1 = acc[b][1] + __shfl_xor(acc[b][1], 32);
        float v2 = acc[b][2] + __shfl_xor(acc[b][2], 32);
        float v3 = acc[b][3] + __shfl_xor(acc[b][3], 32);
        if (hf == 0) {
          unsigned int p0 = splitbf(v0), p1 = splitbf(v1), p2 = splitbf(v2), p3 = splitbf(v3);
          u16x4 hh, ll;
          hh[0] = (u16)p0; ll[0] = (u16)(p0 >> 16);
          hh[1] = (u16)p1; ll[1] = (u16)(p1 >> 16);
          hh[2] = (u16)p2; ll[2] = (u16)(p2 >> 16);
          hh[3] = (u16)p3; ll[3] = (u16)(p3 >> 16);
          int idx = nn * ZK + b * TD + q * 4;
          *reinterpret_cast<u16x4*>(zh + idx) = hh;
          *reinterpret_cast<u16x4*>(zl + idx) = ll;
        }
      }
    }
  }
  __syncthreads();

  // ---- phase 2: MFMA GEMM (R2/R6/R8-exact; rows >= TNB discarded) ----
  const int w = t >> 6, lane = t & 63;
  const int mc = lane & 15, kg = lane >> 4;

  if constexpr (DOUT == 128) {
    f32x4 acc = {0.f, 0.f, 0.f, 0.f};
    {
      const u16* za = zh + mc * ZK + kg * 8;
      const u16* zb = zl + mc * ZK + kg * 8;
      const u16* bha = wth + (size_t)(w * 16 + mc) * TK + kg * 8;
      const u16* bla = wtl + (size_t)(w * 16 + mc) * TK + kg * 8;
#pragma unroll 4
      for (int ks = 0; ks < 32; ++ks) {
        bf16x8 ah  = *(const bf16x8*)(za + 32 * ks);
        bf16x8 alo = *(const bf16x8*)(zb + 32 * ks);
        bf16x8 bh  = *(const bf16x8*)(bha + 32 * ks);
        bf16x8 blo = *(const bf16x8*)(bla + 32 * ks);
        acc = MFMA16(ah, bh, acc);
        acc = MFMA16(alo, bh, acc);
        acc = MFMA16(ah, blo, acc);
      }
      const u16* xa = xh + mc * XK + kg * 8;
      const u16* xb = xl2 + mc * XK + kg * 8;
      const u16* rha = rth + (size_t)(w * 16 + mc) * TD + kg * 8;
      const u16* rla = rtl + (size_t)(w * 16 + mc) * TD + kg * 8;
#pragma unroll
      for (int ks = 0; ks < 4; ++ks) {
        bf16x8 ah  = *(const bf16x8*)(xa + 32 * ks);
        bf16x8 alo = *(const bf16x8*)(xb + 32 * ks);
        bf16x8 bh  = *(const bf16x8*)(rha + 32 * ks);
        bf16x8 blo = *(const bf16x8*)(rla + 32 * ks);
        acc = MFMA16(ah, bh, acc);
        acc = MFMA16(alo, bh, acc);
        acc = MFMA16(ah, blo, acc);
      }
    }
    float bb = bias[w * 16 + mc];
#pragma unroll
    for (int j = 0; j < 4; ++j) {
      int lr = kg * 4 + j;
      int n = n0 + lr;
      if (lr < TNB && n < Ntot) {
        float v = acc[j] + bb;
        if (RELU) v = fmaxf(v, 0.f);
        if constexpr (OUTH16) {
          ((u16*)outv)[(size_t)n * 128 + w * 16 + mc] = f2h(v);
        } else {
          ((float*)outv)[(size_t)n * 128 + w * 16 + mc] = v;
        }
      }
    }
  } else {
    // DOUT == 32: 8-way K-split across waves, both col tiles per wave
    f32x4 a0 = {0.f, 0.f, 0.f, 0.f}, a1 = {0.f, 0.f, 0.f, 0.f};
    {
      const u16* za = zh + mc * ZK + kg * 8;
      const u16* zb = zl + mc * ZK + kg * 8;
      const u16* b0h = wth + (size_t)mc * TK + kg * 8;
      const u16* b0l = wtl + (size_t)mc * TK + kg * 8;
      const u16* b1h = wth + (size_t)(16 + mc) * TK + kg * 8;
      const u16* b1l = wtl + (size_t)(16 + mc) * TK + kg * 8;
#pragma unroll
      for (int i = 0; i < 4; ++i) {
        int ks = w * 4 + i;
        bf16x8 ah  = *(const bf16x8*)(za + 32 * ks);
        bf16x8 alo = *(const bf16x8*)(zb + 32 * ks);
        bf16x8 bh0 = *(const bf16x8*)(b0h + 32 * ks);
        bf16x8 bl0 = *(const bf16x8*)(b0l + 32 * ks);
        bf16x8 bh1 = *(const bf16x8*)(b1h + 32 * ks);
        bf16x8 bl1 = *(const bf16x8*)(b1l + 32 * ks);
        a0 = MFMA16(ah, bh0, a0);
        a0 = MFMA16(alo, bh0, a0);
        a0 = MFMA16(ah, bl0, a0);
        a1 = MFMA16(ah, bh1, a1);
        a1 = MFMA16(alo, bh1, a1);
        a1 = MFMA16(ah, bl1, a1);
      }
      if (w < 4) {
        int ks = w;
        bf16x8 ah  = *(const bf16x8*)(xh + mc * XK + kg * 8 + 32 * ks);
        bf16x8 alo = *(const bf16x8*)(xl2 + mc * XK + kg * 8 + 32 * ks);
        bf16x8 bh0 = *(const bf16x8*)(rth + (size_t)mc * TD + kg * 8 + 32 * ks);
        bf16x8 bl0 = *(const bf16x8*)(rtl + (size_t)mc * TD + kg * 8 + 32 * ks);
        bf16x8 bh1 = *(const bf16x8*)(rth + (size_t)(16 + mc) * TD + kg * 8 + 32 * ks);
        bf16x8 bl1 = *(const bf16x8*)(rtl + (size_t)(16 + mc) * TD + kg * 8 + 32 * ks);
        a0 = MFMA16(ah, bh0, a0);
        a0 = MFMA16(alo, bh0, a0);
        a0 = MFMA16(ah, bl0, a0);
        a1 = MFMA16(ah, bh1, a1);
        a1 = MFMA16(alo, bh1, a1);
        a1 = MFMA16(ah, bl1, a1);
      }
    }
    __syncthreads();                       // all z reads done
    float* pc = (float*)smem;              // [8 waves][2 tiles][256] partials
#pragma unroll
    for (int j = 0; j < 4; ++j) {
      pc[(w * 2 + 0) * 256 + (kg * 4 + j) * 16 + mc] = a0[j];
      pc[(w * 2 + 1) * 256 + (kg * 4 + j) * 16 + mc] = a1[j];
    }
    __syncthreads();
    int row = t >> 5, col = t & 31;
    int tile = col >> 4, cc = col & 15;
    float v = 0.f;
#pragma unroll
    for (int ww = 0; ww < 8; ++ww) v += pc[(ww * 2 + tile) * 256 + row * 16 + cc];
    v += bias[col];
    if constexpr (SOFTMAX) {
      float m = v;
      m = fmaxf(m, __shfl_xor(m, 1));
      m = fmaxf(m, __shfl_xor(m, 2));
      m = fmaxf(m, __shfl_xor(m, 4));
      m = fmaxf(m, __shfl_xor(m, 8));
      m = fmaxf(m, __shfl_xor(m, 16));
      float ev = __expf(v - m);
      float s = ev;
      s += __shfl_xor(s, 1); s += __shfl_xor(s, 2); s += __shfl_xor(s, 4);
      s += __shfl_xor(s, 8); s += __shfl_xor(s, 16);
      v = ev / s;
    }
    int n = n0 + row;
    if (row < TNB && n < Ntot) ((float*)outv)[(size_t)n * 32 + col] = v;
  }
}

extern "C" void kernel_launch(void* const* d_in, const int* in_sizes, int n_in,
                              void* d_out, int out_size, void* d_ws, size_t ws_size,
                              hipStream_t stream) {
  const float* x     = (const float*)d_in[0];
  const float* V1    = (const float*)d_in[1];
  const float* a1    = (const float*)d_in[2];
  const float* root1 = (const float*)d_in[3];
  const float* bias1 = (const float*)d_in[4];
  const float* V2    = (const float*)d_in[5];
  const float* a2    = (const float*)d_in[6];
  const float* root2 = (const float*)d_in[7];
  const float* bias2 = (const float*)d_in[8];
  const int*   ei    = (const int*)d_in[9];    // [2, E]
  const int*   et    = (const int*)d_in[10];   // [E]

  const int N = in_sizes[0] / TD;
  const int E = in_sizes[10];
  const int R = 32;

  char* w = (char*)d_ws;
  auto alloc = [&](size_t bytes) {
    char* p = w;
    w += (bytes + 255) & ~(size_t)255;
    return p;
  };
  int*   off    = (int*)alloc((size_t)(N + 1) * 4);
  int*   cursor = (int*)alloc((size_t)N * 4);
  int*   deg    = (int*)alloc((size_t)N * 4);
  int*   cnt2   = (int*)alloc((size_t)R * N * 4);
  int*   packed = (int*)alloc((size_t)E * 4);
  float* invc   = (float*)alloc((size_t)E * 4);
  u16*   xb     = (u16*)alloc((size_t)N * TD * 2);   // fp16 x (messages)
  u16*   hb     = (u16*)alloc((size_t)N * TD * 2);   // fp16 h
  u16*   v1th   = (u16*)alloc((size_t)128 * 1024 * 2);
  u16*   v1tl   = (u16*)alloc((size_t)128 * 1024 * 2);
  u16*   r1th   = (u16*)alloc((size_t)128 * 128 * 2);
  u16*   r1tl   = (u16*)alloc((size_t)128 * 128 * 2);
  u16*   v2th   = (u16*)alloc((size_t)32 * 1024 * 2);
  u16*   v2tl   = (u16*)alloc((size_t)32 * 1024 * 2);
  u16*   r2th   = (u16*)alloc((size_t)32 * 128 * 2);
  u16*   r2tl   = (u16*)alloc((size_t)32 * 128 * 2);

  hipMemsetAsync(deg, 0, (size_t)N * 4, stream);
  hipMemsetAsync(cnt2, 0, (size_t)R * N * 4, stream);

  k_prep<<<512, 256, 0, stream>>>(V1, root1, V2, root2,
                                  v1th, v1tl, r1th, r1tl, v2th, v2tl, r2th, r2tl);
  int n4 = N * TD / 4;
  k_xcast<<<(n4 + 255) / 256, 256, 0, stream>>>(x, xb, n4);

  int egrid = (E + 255) / 256;
  k_hist<<<egrid, 256, 0, stream>>>(ei, et, deg, cnt2, E, N);
  k_scan<<<1, 1024, 0, stream>>>(deg, off, cursor, N, E);
  k_scatter<<<egrid, 256, 0, stream>>>(ei, et, cursor, cnt2, packed, invc, E, N);

  const size_t shmem = (size_t)(2 * TNB * ZK + 2 * TNB * XK) * 2 + 256 * 4;
  (void)hipFuncSetAttribute(reinterpret_cast<const void*>(&k_layer<128, true, false, true, true>),
                            hipFuncAttributeMaxDynamicSharedMemorySize, (int)shmem);
  (void)hipFuncSetAttribute(reinterpret_cast<const void*>(&k_layer<32, false, true, false, false>),
                            hipFuncAttributeMaxDynamicSharedMemorySize, (int)shmem);

  int ngrid = (N + TNB - 1) / TNB;
  k_layer<128, true, false, true, true><<<ngrid, BLK, shmem, stream>>>(
      x, xb, v1th, v1tl, a1, r1th, r1tl, bias1, off, packed, invc, hb, N);
  k_layer<32, false, true, false, false><<<ngrid, BLK, shmem, stream>>>(
      nullptr, hb, v2th, v2tl, a2, r2th, r2tl, bias2, off, packed, invc, d_out, N);
}

// Round 13
// 859.429 us; speedup vs baseline: 1.4136x; 1.4136x over previous
//
#include <hip/hip_runtime.h>
#include <hip/hip_bf16.h>
#include <hip/hip_fp16.h>

// RGCN 2-layer, basis-decomposed.
// R12 = R11 (correct, TNB=8, 4 blocks/CU by LDS) with launch_bounds back to
// (512,4): R11's (512,8) capped VGPR at 64 -> scratch spill (947MB writes).
// (512,4) keeps the 128-VGPR budget (kernel uses ~48); occupancy still 4
// blocks/CU via LDS (38KB) since bounds arg is a minimum, not a cap.

typedef __attribute__((ext_vector_type(8))) short bf16x8;
typedef __attribute__((ext_vector_type(4))) float f32x4;
typedef unsigned short u16;
typedef __attribute__((ext_vector_type(4))) unsigned short u16x4;

constexpr int TD   = 128;        // feature dim (both layers' input dim)
constexpr int TB   = 8;          // bases
constexpr int TK   = TB * TD;    // 1024
constexpr int TNB  = 8;          // nodes per block (half-filled MFMA M)
constexpr int BLK  = 512;        // 8 waves
constexpr int ZK   = TK + 8;     // ushort stride for z rows (2064 B)
constexpr int XK   = TD + 8;     // ushort stride for x rows

// returns (hi, lo) bf16 pair packed: hi in low 16, lo in high 16
__device__ inline unsigned int splitbf(float v) {
  unsigned int u = __float_as_uint(v);
  unsigned int r = u + 0x7FFF + ((u >> 16) & 1);   // rne to bf16
  unsigned int hb = r >> 16;
  float hv = __uint_as_float(hb << 16);
  float lo = v - hv;
  unsigned int u2 = __float_as_uint(lo);
  unsigned int r2 = u2 + 0x7FFF + ((u2 >> 16) & 1);
  return (hb & 0xFFFFu) | (r2 & 0xFFFF0000u);
}

__device__ inline u16 f2h(float v) { return __half_as_ushort(__float2half(v)); }
__device__ inline float h2f(u16 b) { return __half2float(__ushort_as_half(b)); }

// W[k][o] -> WT_hi/lo[o][k]
__global__ void k_prep(const float* __restrict__ V1, const float* __restrict__ root1,
                       const float* __restrict__ V2, const float* __restrict__ root2,
                       u16* __restrict__ v1th, u16* __restrict__ v1tl,
                       u16* __restrict__ r1th, u16* __restrict__ r1tl,
                       u16* __restrict__ v2th, u16* __restrict__ v2tl,
                       u16* __restrict__ r2th, u16* __restrict__ r2tl) {
  int idx = blockIdx.x * 256 + threadIdx.x;
  if (idx < 128 * 1024) {
    unsigned int p = splitbf(V1[(size_t)(idx & 1023) * 128 + (idx >> 10)]);
    v1th[idx] = (u16)p; v1tl[idx] = (u16)(p >> 16);
  }
  if (idx < 128 * 128) {
    unsigned int p = splitbf(root1[(size_t)(idx & 127) * 128 + (idx >> 7)]);
    r1th[idx] = (u16)p; r1tl[idx] = (u16)(p >> 16);
  }
  if (idx < 32 * 1024) {
    unsigned int p = splitbf(V2[(size_t)(idx & 1023) * 32 + (idx >> 10)]);
    v2th[idx] = (u16)p; v2tl[idx] = (u16)(p >> 16);
  }
  if (idx < 32 * 128) {
    unsigned int p = splitbf(root2[(size_t)(idx & 127) * 32 + (idx >> 7)]);
    r2th[idx] = (u16)p; r2tl[idx] = (u16)(p >> 16);
  }
}

// f32 x -> fp16 xb (message copy), 4 elems/thread
__global__ void k_xcast(const float* __restrict__ x, u16* __restrict__ xb, int n4) {
  int i = blockIdx.x * 256 + threadIdx.x;
  if (i >= n4) return;
  float4 v = reinterpret_cast<const float4*>(x)[i];
  u16x4 o;
  o[0] = f2h(v.x); o[1] = f2h(v.y); o[2] = f2h(v.z); o[3] = f2h(v.w);
  reinterpret_cast<u16x4*>(xb)[i] = o;
}

__global__ void k_hist(const int* __restrict__ ei, const int* __restrict__ et,
                       int* __restrict__ deg, int* __restrict__ cnt2,
                       int E, int N) {
  int e = blockIdx.x * 256 + threadIdx.x;
  if (e >= E) return;
  int d = ei[E + e];
  int r = et[e];
  atomicAdd(&deg[d], 1);
  atomicAdd(&cnt2[r * N + d], 1);
}

__global__ void k_scan(const int* __restrict__ deg, int* __restrict__ off,
                       int* __restrict__ cursor, int n, int total) {
  __shared__ int wsum[16];
  __shared__ int carry_s;
  const int t = threadIdx.x, lane = t & 63, w = t >> 6;
  if (t == 0) carry_s = 0;
  __syncthreads();
  for (int base = 0; base < n; base += 1024) {
    int i = base + t;
    int v = (i < n) ? deg[i] : 0;
    int s = v;
#pragma unroll
    for (int d = 1; d < 64; d <<= 1) {
      int u = __shfl_up(s, d);
      if (lane >= d) s += u;
    }
    if (lane == 63) wsum[w] = s;
    __syncthreads();
    if (w == 0) {
      int ws = (lane < 16) ? wsum[lane] : 0;
#pragma unroll
      for (int d = 1; d < 16; d <<= 1) {
        int u = __shfl_up(ws, d);
        if (lane >= d) ws += u;
      }
      if (lane < 16) wsum[lane] = ws;
    }
    __syncthreads();
    int wbase = (w == 0) ? 0 : wsum[w - 1];
    int carry = carry_s;
    if (i < n) { int ex = carry + wbase + s - v; off[i] = ex; cursor[i] = ex; }
    __syncthreads();
    if (t == 1023) carry_s = carry + wbase + s;
    __syncthreads();
  }
  if (t == 0) off[n] = total;
}

__global__ void k_scatter(const int* __restrict__ ei, const int* __restrict__ et,
                          int* __restrict__ cursor, const int* __restrict__ cnt2,
                          int* __restrict__ packed, float* __restrict__ invc,
                          int E, int N) {
  int e = blockIdx.x * 256 + threadIdx.x;
  if (e >= E) return;
  int s = ei[e], d = ei[E + e], r = et[e];
  int p = atomicAdd(&cursor[d], 1);
  packed[p] = s | (r << 17);
  invc[p] = 1.0f / (float)cnt2[r * N + d];
}

#define MFMA16(A, B, C) __builtin_amdgcn_mfma_f32_16x16x32_bf16((A), (B), (C), 0, 0, 0)

template <int DOUT, bool RELU, bool SOFTMAX, bool INF32, bool OUTH16>
__global__ __launch_bounds__(BLK, 4) void k_layer(
    const float* __restrict__ inf,       // f32 features (layer 1 x-tile)
    const u16* __restrict__ inb,         // fp16 features (gather; layer-2 x-tile)
    const u16* __restrict__ wth, const u16* __restrict__ wtl,    // [DOUT][TK]
    const float* __restrict__ a,
    const u16* __restrict__ rth, const u16* __restrict__ rtl,    // [DOUT][TD]
    const float* __restrict__ bias, const int* __restrict__ off,
    const int* __restrict__ packed, const float* __restrict__ invc,
    void* __restrict__ outv, int Ntot) {
  extern __shared__ char smem[];
  u16* zh = (u16*)smem;                 // [TNB][ZK]
  u16* zl = zh + TNB * ZK;
  u16* xh = zl + TNB * ZK;              // [TNB][XK]
  u16* xl2 = xh + TNB * XK;
  float* ash = (float*)(xl2 + TNB * XK);  // [256] = a[R][B]
  const int t = threadIdx.x;
  const int n0 = blockIdx.x * TNB;

  if (t < 256) ash[t] = a[t];
  // stage x tile as hi/lo (TNB=8 rows, 256 threads)
  if (t < TNB * 32) {
    int row = t >> 5;
    int c4 = (t & 31) * 4;
    int n = n0 + row;
    float4 v = make_float4(0.f, 0.f, 0.f, 0.f);
    if constexpr (INF32) {
      if (n < Ntot) v = *reinterpret_cast<const float4*>(inf + (size_t)n * TD + c4);
    } else {
      if (n < Ntot) {
        u16x4 hv = *reinterpret_cast<const u16x4*>(inb + (size_t)n * TD + c4);
        v = make_float4(h2f(hv[0]), h2f(hv[1]), h2f(hv[2]), h2f(hv[3]));
      }
    }
    unsigned int p0 = splitbf(v.x), p1 = splitbf(v.y), p2 = splitbf(v.z), p3 = splitbf(v.w);
    xh[row * XK + c4]     = (u16)p0; xl2[row * XK + c4]     = (u16)(p0 >> 16);
    xh[row * XK + c4 + 1] = (u16)p1; xl2[row * XK + c4 + 1] = (u16)(p1 >> 16);
    xh[row * XK + c4 + 2] = (u16)p2; xl2[row * XK + c4 + 2] = (u16)(p2 >> 16);
    xh[row * XK + c4 + 3] = (u16)p3; xl2[row * XK + c4 + 3] = (u16)(p3 >> 16);
  }
  __syncthreads();

  // ---- phase 1: half-wave-per-edge fp16 gather, 2-deep ping-pong ----
  // 1 node per wave (TNB == 8 waves count)
  {
    const int wv = t >> 6, lane = t & 63;
    const int hf = lane >> 5, q = lane & 31;
    const int nn = wv;
    {
      int n = n0 + nn;
      float acc[8][4];
#pragma unroll
      for (int b = 0; b < 8; ++b)
#pragma unroll
        for (int j = 0; j < 4; ++j) acc[b][j] = 0.f;

      if (n < Ntot) {
        int e0 = off[n], e1 = off[n + 1];
        int np = (e1 - e0 + 1) >> 1;

        struct Pk { float4 xv, c0, c1; };
        auto ldst = [&](int pe) {
          Pk P;
          int e = e0 + 2 * pe + hf;
          float iv = 0.f; int r = 0;
          u16x4 xr = {0, 0, 0, 0};
          if (e < e1) {
            int pk = packed[e];
            iv = invc[e];
            r = pk >> 17;
            xr = *reinterpret_cast<const u16x4*>(inb + (size_t)(pk & 131071) * TD + q * 4);
          }
          P.xv = make_float4(h2f(xr[0]), h2f(xr[1]), h2f(xr[2]), h2f(xr[3]));
          float4 t0 = *reinterpret_cast<const float4*>(ash + r * 8);
          float4 t1 = *reinterpret_cast<const float4*>(ash + r * 8 + 4);
          P.c0 = make_float4(t0.x * iv, t0.y * iv, t0.z * iv, t0.w * iv);
          P.c1 = make_float4(t1.x * iv, t1.y * iv, t1.z * iv, t1.w * iv);
          return P;
        };
        auto comp = [&](const Pk& P) {
#define ACCB(bi, cc) \
          acc[bi][0] += (cc) * P.xv.x; acc[bi][1] += (cc) * P.xv.y; \
          acc[bi][2] += (cc) * P.xv.z; acc[bi][3] += (cc) * P.xv.w;
          ACCB(0, P.c0.x) ACCB(1, P.c0.y) ACCB(2, P.c0.z) ACCB(3, P.c0.w)
          ACCB(4, P.c1.x) ACCB(5, P.c1.y) ACCB(6, P.c1.z) ACCB(7, P.c1.w)
#undef ACCB
        };

        Pk A, B;
        if (np > 0) A = ldst(0);
        if (np > 1) B = ldst(1);
        for (int pe = 0; pe < np; pe += 2) {
          comp(A);
          if (pe + 2 < np) A = ldst(pe + 2);
          if (pe + 1 < np) {
            comp(B);
            if (pe + 3 < np) B = ldst(pe + 3);
          }
        }
      }

      // cross-half reduce; hf==0 lanes write BOTH hi and lo
#pragma unroll
      for (int b = 0; b < 8; ++b) {
        float v0 = acc[b][0] + __shfl_xor(acc[b][0], 32);
        float v1 = acc[b][1] + __shfl_xor(acc[b][1], 32);
        float v2 = acc[b][2] + __shfl_xor(acc[b][2], 32);
        float v3 = acc[b][3] + __shfl_xor(acc[b][3], 32);
        if (hf == 0) {
          unsigned int p0 = splitbf(v0), p1 = splitbf(v1), p2 = splitbf(v2), p3 = splitbf(v3);
          u16x4 hh, ll;
          hh[0] = (u16)p0; ll[0] = (u16)(p0 >> 16);
          hh[1] = (u16)p1; ll[1] = (u16)(p1 >> 16);
          hh[2] = (u16)p2; ll[2] = (u16)(p2 >> 16);
          hh[3] = (u16)p3; ll[3] = (u16)(p3 >> 16);
          int idx = nn * ZK + b * TD + q * 4;
          *reinterpret_cast<u16x4*>(zh + idx) = hh;
          *reinterpret_cast<u16x4*>(zl + idx) = ll;
        }
      }
    }
  }
  __syncthreads();

  // ---- phase 2: MFMA GEMM (R2/R6/R8-exact; rows >= TNB discarded) ----
  const int w = t >> 6, lane = t & 63;
  const int mc = lane & 15, kg = lane >> 4;

  if constexpr (DOUT == 128) {
    f32x4 acc = {0.f, 0.f, 0.f, 0.f};
    {
      const u16* za = zh + mc * ZK + kg * 8;
      const u16* zb = zl + mc * ZK + kg * 8;
      const u16* bha = wth + (size_t)(w * 16 + mc) * TK + kg * 8;
      const u16* bla = wtl + (size_t)(w * 16 + mc) * TK + kg * 8;
#pragma unroll 4
      for (int ks = 0; ks < 32; ++ks) {
        bf16x8 ah  = *(const bf16x8*)(za + 32 * ks);
        bf16x8 alo = *(const bf16x8*)(zb + 32 * ks);
        bf16x8 bh  = *(const bf16x8*)(bha + 32 * ks);
        bf16x8 blo = *(const bf16x8*)(bla + 32 * ks);
        acc = MFMA16(ah, bh, acc);
        acc = MFMA16(alo, bh, acc);
        acc = MFMA16(ah, blo, acc);
      }
      const u16* xa = xh + mc * XK + kg * 8;
      const u16* xb = xl2 + mc * XK + kg * 8;
      const u16* rha = rth + (size_t)(w * 16 + mc) * TD + kg * 8;
      const u16* rla = rtl + (size_t)(w * 16 + mc) * TD + kg * 8;
#pragma unroll
      for (int ks = 0; ks < 4; ++ks) {
        bf16x8 ah  = *(const bf16x8*)(xa + 32 * ks);
        bf16x8 alo = *(const bf16x8*)(xb + 32 * ks);
        bf16x8 bh  = *(const bf16x8*)(rha + 32 * ks);
        bf16x8 blo = *(const bf16x8*)(rla + 32 * ks);
        acc = MFMA16(ah, bh, acc);
        acc = MFMA16(alo, bh, acc);
        acc = MFMA16(ah, blo, acc);
      }
    }
    float bb = bias[w * 16 + mc];
#pragma unroll
    for (int j = 0; j < 4; ++j) {
      int lr = kg * 4 + j;
      int n = n0 + lr;
      if (lr < TNB && n < Ntot) {
        float v = acc[j] + bb;
        if (RELU) v = fmaxf(v, 0.f);
        if constexpr (OUTH16) {
          ((u16*)outv)[(size_t)n * 128 + w * 16 + mc] = f2h(v);
        } else {
          ((float*)outv)[(size_t)n * 128 + w * 16 + mc] = v;
        }
      }
    }
  } else {
    // DOUT == 32: 8-way K-split across waves, both col tiles per wave
    f32x4 a0 = {0.f, 0.f, 0.f, 0.f}, a1 = {0.f, 0.f, 0.f, 0.f};
    {
      const u16* za = zh + mc * ZK + kg * 8;
      const u16* zb = zl + mc * ZK + kg * 8;
      const u16* b0h = wth + (size_t)mc * TK + kg * 8;
      const u16* b0l = wtl + (size_t)mc * TK + kg * 8;
      const u16* b1h = wth + (size_t)(16 + mc) * TK + kg * 8;
      const u16* b1l = wtl + (size_t)(16 + mc) * TK + kg * 8;
#pragma unroll
      for (int i = 0; i < 4; ++i) {
        int ks = w * 4 + i;
        bf16x8 ah  = *(const bf16x8*)(za + 32 * ks);
        bf16x8 alo = *(const bf16x8*)(zb + 32 * ks);
        bf16x8 bh0 = *(const bf16x8*)(b0h + 32 * ks);
        bf16x8 bl0 = *(const bf16x8*)(b0l + 32 * ks);
        bf16x8 bh1 = *(const bf16x8*)(b1h + 32 * ks);
        bf16x8 bl1 = *(const bf16x8*)(b1l + 32 * ks);
        a0 = MFMA16(ah, bh0, a0);
        a0 = MFMA16(alo, bh0, a0);
        a0 = MFMA16(ah, bl0, a0);
        a1 = MFMA16(ah, bh1, a1);
        a1 = MFMA16(alo, bh1, a1);
        a1 = MFMA16(ah, bl1, a1);
      }
      if (w < 4) {
        int ks = w;
        bf16x8 ah  = *(const bf16x8*)(xh + mc * XK + kg * 8 + 32 * ks);
        bf16x8 alo = *(const bf16x8*)(xl2 + mc * XK + kg * 8 + 32 * ks);
        bf16x8 bh0 = *(const bf16x8*)(rth + (size_t)mc * TD + kg * 8 + 32 * ks);
        bf16x8 bl0 = *(const bf16x8*)(rtl + (size_t)mc * TD + kg * 8 + 32 * ks);
        bf16x8 bh1 = *(const bf16x8*)(rth + (size_t)(16 + mc) * TD + kg * 8 + 32 * ks);
        bf16x8 bl1 = *(const bf16x8*)(rtl + (size_t)(16 + mc) * TD + kg * 8 + 32 * ks);
        a0 = MFMA16(ah, bh0, a0);
        a0 = MFMA16(alo, bh0, a0);
        a0 = MFMA16(ah, bl0, a0);
        a1 = MFMA16(ah, bh1, a1);
        a1 = MFMA16(alo, bh1, a1);
        a1 = MFMA16(ah, bl1, a1);
      }
    }
    __syncthreads();                       // all z reads done
    float* pc = (float*)smem;              // [8 waves][2 tiles][256] partials
#pragma unroll
    for (int j = 0; j < 4; ++j) {
      pc[(w * 2 + 0) * 256 + (kg * 4 + j) * 16 + mc] = a0[j];
      pc[(w * 2 + 1) * 256 + (kg * 4 + j) * 16 + mc] = a1[j];
    }
    __syncthreads();
    int row = t >> 5, col = t & 31;
    int tile = col >> 4, cc = col & 15;
    float v = 0.f;
#pragma unroll
    for (int ww = 0; ww < 8; ++ww) v += pc[(ww * 2 + tile) * 256 + row * 16 + cc];
    v += bias[col];
    if constexpr (SOFTMAX) {
      float m = v;
      m = fmaxf(m, __shfl_xor(m, 1));
      m = fmaxf(m, __shfl_xor(m, 2));
      m = fmaxf(m, __shfl_xor(m, 4));
      m = fmaxf(m, __shfl_xor(m, 8));
      m = fmaxf(m, __shfl_xor(m, 16));
      float ev = __expf(v - m);
      float s = ev;
      s += __shfl_xor(s, 1); s += __shfl_xor(s, 2); s += __shfl_xor(s, 4);
      s += __shfl_xor(s, 8); s += __shfl_xor(s, 16);
      v = ev / s;
    }
    int n = n0 + row;
    if (row < TNB && n < Ntot) ((float*)outv)[(size_t)n * 32 + col] = v;
  }
}

extern "C" void kernel_launch(void* const* d_in, const int* in_sizes, int n_in,
                              void* d_out, int out_size, void* d_ws, size_t ws_size,
                              hipStream_t stream) {
  const float* x     = (const float*)d_in[0];
  const float* V1    = (const float*)d_in[1];
  const float* a1    = (const float*)d_in[2];
  const float* root1 = (const float*)d_in[3];
  const float* bias1 = (const float*)d_in[4];
  const float* V2    = (const float*)d_in[5];
  const float* a2    = (const float*)d_in[6];
  const float* root2 = (const float*)d_in[7];
  const float* bias2 = (const float*)d_in[8];
  const int*   ei    = (const int*)d_in[9];    // [2, E]
  const int*   et    = (const int*)d_in[10];   // [E]

  const int N = in_sizes[0] / TD;
  const int E = in_sizes[10];
  const int R = 32;

  char* w = (char*)d_ws;
  auto alloc = [&](size_t bytes) {
    char* p = w;
    w += (bytes + 255) & ~(size_t)255;
    return p;
  };
  int*   off    = (int*)alloc((size_t)(N + 1) * 4);
  int*   cursor = (int*)alloc((size_t)N * 4);
  int*   deg    = (int*)alloc((size_t)N * 4);
  int*   cnt2   = (int*)alloc((size_t)R * N * 4);
  int*   packed = (int*)alloc((size_t)E * 4);
  float* invc   = (float*)alloc((size_t)E * 4);
  u16*   xb     = (u16*)alloc((size_t)N * TD * 2);   // fp16 x (messages)
  u16*   hb     = (u16*)alloc((size_t)N * TD * 2);   // fp16 h
  u16*   v1th   = (u16*)alloc((size_t)128 * 1024 * 2);
  u16*   v1tl   = (u16*)alloc((size_t)128 * 1024 * 2);
  u16*   r1th   = (u16*)alloc((size_t)128 * 128 * 2);
  u16*   r1tl   = (u16*)alloc((size_t)128 * 128 * 2);
  u16*   v2th   = (u16*)alloc((size_t)32 * 1024 * 2);
  u16*   v2tl   = (u16*)alloc((size_t)32 * 1024 * 2);
  u16*   r2th   = (u16*)alloc((size_t)32 * 128 * 2);
  u16*   r2tl   = (u16*)alloc((size_t)32 * 128 * 2);

  hipMemsetAsync(deg, 0, (size_t)N * 4, stream);
  hipMemsetAsync(cnt2, 0, (size_t)R * N * 4, stream);

  k_prep<<<512, 256, 0, stream>>>(V1, root1, V2, root2,
                                  v1th, v1tl, r1th, r1tl, v2th, v2tl, r2th, r2tl);
  int n4 = N * TD / 4;
  k_xcast<<<(n4 + 255) / 256, 256, 0, stream>>>(x, xb, n4);

  int egrid = (E + 255) / 256;
  k_hist<<<egrid, 256, 0, stream>>>(ei, et, deg, cnt2, E, N);
  k_scan<<<1, 1024, 0, stream>>>(deg, off, cursor, N, E);
  k_scatter<<<egrid, 256, 0, stream>>>(ei, et, cursor, cnt2, packed, invc, E, N);

  const size_t shmem = (size_t)(2 * TNB * ZK + 2 * TNB * XK) * 2 + 256 * 4;
  (void)hipFuncSetAttribute(reinterpret_cast<const void*>(&k_layer<128, true, false, true, true>),
                            hipFuncAttributeMaxDynamicSharedMemorySize, (int)shmem);
  (void)hipFuncSetAttribute(reinterpret_cast<const void*>(&k_layer<32, false, true, false, false>),
                            hipFuncAttributeMaxDynamicSharedMemorySize, (int)shmem);

  int ngrid = (N + TNB - 1) / TNB;
  k_layer<128, true, false, true, true><<<ngrid, BLK, shmem, stream>>>(
      x, xb, v1th, v1tl, a1, r1th, r1tl, bias1, off, packed, invc, hb, N);
  k_layer<32, false, true, false, false><<<ngrid, BLK, shmem, stream>>>(
      nullptr, hb, v2th, v2tl, a2, r2th, r2tl, bias2, off, packed, invc, d_out, N);
}

// Round 14
// 578.496 us; speedup vs baseline: 2.1001x; 1.4856x over previous
//
#include <hip/hip_runtime.h>
#include <hip/hip_bf16.h>
#include <hip/hip_fp16.h>

// RGCN 2-layer, basis-decomposed.
// R13 = R8 (verified, TNB=16) + LDS edge-record cache (breaks the
// packed[e] -> row-address vmcnt chain) + depth-4 ping-pong (R10-verified).
// Block's edge records are contiguous (dst-sorted) -> one coalesced stage.

typedef __attribute__((ext_vector_type(8))) short bf16x8;
typedef __attribute__((ext_vector_type(4))) float f32x4;
typedef unsigned short u16;
typedef __attribute__((ext_vector_type(4))) unsigned short u16x4;

constexpr int TD   = 128;        // feature dim (both layers' input dim)
constexpr int TB   = 8;          // bases
constexpr int TK   = TB * TD;    // 1024
constexpr int TNB  = 16;         // nodes per block
constexpr int BLK  = 512;        // 8 waves
constexpr int ZK   = TK + 8;     // ushort stride for z rows (2064 B)
constexpr int XK   = TD + 8;     // ushort stride for x rows
constexpr int EC   = 512;        // LDS edge-record cache (avg ~192/block)

// returns (hi, lo) bf16 pair packed: hi in low 16, lo in high 16
__device__ inline unsigned int splitbf(float v) {
  unsigned int u = __float_as_uint(v);
  unsigned int r = u + 0x7FFF + ((u >> 16) & 1);   // rne to bf16
  unsigned int hb = r >> 16;
  float hv = __uint_as_float(hb << 16);
  float lo = v - hv;
  unsigned int u2 = __float_as_uint(lo);
  unsigned int r2 = u2 + 0x7FFF + ((u2 >> 16) & 1);
  return (hb & 0xFFFFu) | (r2 & 0xFFFF0000u);
}

__device__ inline u16 f2h(float v) { return __half_as_ushort(__float2half(v)); }
__device__ inline float h2f(u16 b) { return __half2float(__ushort_as_half(b)); }

// W[k][o] -> WT_hi/lo[o][k]
__global__ void k_prep(const float* __restrict__ V1, const float* __restrict__ root1,
                       const float* __restrict__ V2, const float* __restrict__ root2,
                       u16* __restrict__ v1th, u16* __restrict__ v1tl,
                       u16* __restrict__ r1th, u16* __restrict__ r1tl,
                       u16* __restrict__ v2th, u16* __restrict__ v2tl,
                       u16* __restrict__ r2th, u16* __restrict__ r2tl) {
  int idx = blockIdx.x * 256 + threadIdx.x;
  if (idx < 128 * 1024) {
    unsigned int p = splitbf(V1[(size_t)(idx & 1023) * 128 + (idx >> 10)]);
    v1th[idx] = (u16)p; v1tl[idx] = (u16)(p >> 16);
  }
  if (idx < 128 * 128) {
    unsigned int p = splitbf(root1[(size_t)(idx & 127) * 128 + (idx >> 7)]);
    r1th[idx] = (u16)p; r1tl[idx] = (u16)(p >> 16);
  }
  if (idx < 32 * 1024) {
    unsigned int p = splitbf(V2[(size_t)(idx & 1023) * 32 + (idx >> 10)]);
    v2th[idx] = (u16)p; v2tl[idx] = (u16)(p >> 16);
  }
  if (idx < 32 * 128) {
    unsigned int p = splitbf(root2[(size_t)(idx & 127) * 32 + (idx >> 7)]);
    r2th[idx] = (u16)p; r2tl[idx] = (u16)(p >> 16);
  }
}

// f32 x -> fp16 xb (message copy), 4 elems/thread
__global__ void k_xcast(const float* __restrict__ x, u16* __restrict__ xb, int n4) {
  int i = blockIdx.x * 256 + threadIdx.x;
  if (i >= n4) return;
  float4 v = reinterpret_cast<const float4*>(x)[i];
  u16x4 o;
  o[0] = f2h(v.x); o[1] = f2h(v.y); o[2] = f2h(v.z); o[3] = f2h(v.w);
  reinterpret_cast<u16x4*>(xb)[i] = o;
}

__global__ void k_hist(const int* __restrict__ ei, const int* __restrict__ et,
                       int* __restrict__ deg, int* __restrict__ cnt2,
                       int E, int N) {
  int e = blockIdx.x * 256 + threadIdx.x;
  if (e >= E) return;
  int d = ei[E + e];
  int r = et[e];
  atomicAdd(&deg[d], 1);
  atomicAdd(&cnt2[r * N + d], 1);
}

__global__ void k_scan(const int* __restrict__ deg, int* __restrict__ off,
                       int* __restrict__ cursor, int n, int total) {
  __shared__ int wsum[16];
  __shared__ int carry_s;
  const int t = threadIdx.x, lane = t & 63, w = t >> 6;
  if (t == 0) carry_s = 0;
  __syncthreads();
  for (int base = 0; base < n; base += 1024) {
    int i = base + t;
    int v = (i < n) ? deg[i] : 0;
    int s = v;
#pragma unroll
    for (int d = 1; d < 64; d <<= 1) {
      int u = __shfl_up(s, d);
      if (lane >= d) s += u;
    }
    if (lane == 63) wsum[w] = s;
    __syncthreads();
    if (w == 0) {
      int ws = (lane < 16) ? wsum[lane] : 0;
#pragma unroll
      for (int d = 1; d < 16; d <<= 1) {
        int u = __shfl_up(ws, d);
        if (lane >= d) ws += u;
      }
      if (lane < 16) wsum[lane] = ws;
    }
    __syncthreads();
    int wbase = (w == 0) ? 0 : wsum[w - 1];
    int carry = carry_s;
    if (i < n) { int ex = carry + wbase + s - v; off[i] = ex; cursor[i] = ex; }
    __syncthreads();
    if (t == 1023) carry_s = carry + wbase + s;
    __syncthreads();
  }
  if (t == 0) off[n] = total;
}

__global__ void k_scatter(const int* __restrict__ ei, const int* __restrict__ et,
                          int* __restrict__ cursor, const int* __restrict__ cnt2,
                          int* __restrict__ packed, float* __restrict__ invc,
                          int E, int N) {
  int e = blockIdx.x * 256 + threadIdx.x;
  if (e >= E) return;
  int s = ei[e], d = ei[E + e], r = et[e];
  int p = atomicAdd(&cursor[d], 1);
  packed[p] = s | (r << 17);
  invc[p] = 1.0f / (float)cnt2[r * N + d];
}

#define MFMA16(A, B, C) __builtin_amdgcn_mfma_f32_16x16x32_bf16((A), (B), (C), 0, 0, 0)

template <int DOUT, bool RELU, bool SOFTMAX, bool INF32, bool OUTH16>
__global__ __launch_bounds__(BLK, 4) void k_layer(
    const float* __restrict__ inf,       // f32 features (layer 1 x-tile)
    const u16* __restrict__ inb,         // fp16 features (gather; layer-2 x-tile)
    const u16* __restrict__ wth, const u16* __restrict__ wtl,    // [DOUT][TK]
    const float* __restrict__ a,
    const u16* __restrict__ rth, const u16* __restrict__ rtl,    // [DOUT][TD]
    const float* __restrict__ bias, const int* __restrict__ off,
    const int* __restrict__ packed, const float* __restrict__ invc,
    void* __restrict__ outv, int Ntot) {
  extern __shared__ char smem[];
  u16* zh = (u16*)smem;                 // [TNB][ZK]
  u16* zl = zh + TNB * ZK;
  u16* xh = zl + TNB * ZK;              // [TNB][XK]
  u16* xl2 = xh + TNB * XK;
  float* ash = (float*)(xl2 + TNB * XK);  // [256] = a[R][B]
  int*   lrp = (int*)(ash + 256);         // [EC] packed cache
  float* lri = (float*)(lrp + EC);        // [EC] invc cache
  const int t = threadIdx.x;
  const int n0 = blockIdx.x * TNB;

  if (t < 256) ash[t] = a[t];
  // stage x tile as hi/lo
  {
    int row = t >> 5;
    int c4 = (t & 31) * 4;
    int n = n0 + row;
    float4 v = make_float4(0.f, 0.f, 0.f, 0.f);
    if constexpr (INF32) {
      if (n < Ntot) v = *reinterpret_cast<const float4*>(inf + (size_t)n * TD + c4);
    } else {
      if (n < Ntot) {
        u16x4 hv = *reinterpret_cast<const u16x4*>(inb + (size_t)n * TD + c4);
        v = make_float4(h2f(hv[0]), h2f(hv[1]), h2f(hv[2]), h2f(hv[3]));
      }
    }
    unsigned int p0 = splitbf(v.x), p1 = splitbf(v.y), p2 = splitbf(v.z), p3 = splitbf(v.w);
    xh[row * XK + c4]     = (u16)p0; xl2[row * XK + c4]     = (u16)(p0 >> 16);
    xh[row * XK + c4 + 1] = (u16)p1; xl2[row * XK + c4 + 1] = (u16)(p1 >> 16);
    xh[row * XK + c4 + 2] = (u16)p2; xl2[row * XK + c4 + 2] = (u16)(p2 >> 16);
    xh[row * XK + c4 + 3] = (u16)p3; xl2[row * XK + c4 + 3] = (u16)(p3 >> 16);
  }
  // stage the block's edge records into LDS (contiguous after dst-sort)
  const int e_start = off[n0 < Ntot ? n0 : Ntot];
  {
    int nend = n0 + TNB; if (nend > Ntot) nend = Ntot;
    int ec = off[nend] - e_start;
    if (ec > EC) ec = EC;
    for (int i = t; i < ec; i += BLK) {
      lrp[i] = packed[e_start + i];
      lri[i] = invc[e_start + i];
    }
  }
  __syncthreads();

  // ---- phase 1: half-wave-per-edge fp16 gather, 4-deep ping-pong ----
  {
    const int wv = t >> 6, lane = t & 63;
    const int hf = lane >> 5, q = lane & 31;

    for (int nn = wv * 2; nn < wv * 2 + 2; ++nn) {
      int n = n0 + nn;
      float acc[8][4];
#pragma unroll
      for (int b = 0; b < 8; ++b)
#pragma unroll
        for (int j = 0; j < 4; ++j) acc[b][j] = 0.f;

      if (n < Ntot) {
        int e0 = off[n], e1 = off[n + 1];
        int np = (e1 - e0 + 1) >> 1;

        struct Pk { float4 xv, c0, c1; };
        auto ldst = [&](int pe) {
          Pk P;
          int e = e0 + 2 * pe + hf;
          float iv = 0.f; int r = 0;
          u16x4 xr = {0, 0, 0, 0};
          if (e < e1) {
            int le = e - e_start;
            int pk;
            if (le < EC) { pk = lrp[le]; iv = lri[le]; }
            else         { pk = packed[e]; iv = invc[e]; }
            r = pk >> 17;
            xr = *reinterpret_cast<const u16x4*>(inb + (size_t)(pk & 131071) * TD + q * 4);
          }
          P.xv = make_float4(h2f(xr[0]), h2f(xr[1]), h2f(xr[2]), h2f(xr[3]));
          float4 t0 = *reinterpret_cast<const float4*>(ash + r * 8);
          float4 t1 = *reinterpret_cast<const float4*>(ash + r * 8 + 4);
          P.c0 = make_float4(t0.x * iv, t0.y * iv, t0.z * iv, t0.w * iv);
          P.c1 = make_float4(t1.x * iv, t1.y * iv, t1.z * iv, t1.w * iv);
          return P;
        };
        auto comp = [&](const Pk& P) {
#define ACCB(bi, cc) \
          acc[bi][0] += (cc) * P.xv.x; acc[bi][1] += (cc) * P.xv.y; \
          acc[bi][2] += (cc) * P.xv.z; acc[bi][3] += (cc) * P.xv.w;
          ACCB(0, P.c0.x) ACCB(1, P.c0.y) ACCB(2, P.c0.z) ACCB(3, P.c0.w)
          ACCB(4, P.c1.x) ACCB(5, P.c1.y) ACCB(6, P.c1.z) ACCB(7, P.c1.w)
#undef ACCB
        };

        Pk A, B, C, D;
        if (np > 0) A = ldst(0);
        if (np > 1) B = ldst(1);
        if (np > 2) C = ldst(2);
        if (np > 3) D = ldst(3);
        for (int pe = 0; pe < np; pe += 4) {
          comp(A);
          if (pe + 4 < np) A = ldst(pe + 4);
          if (pe + 1 < np) {
            comp(B);
            if (pe + 5 < np) B = ldst(pe + 5);
          }
          if (pe + 2 < np) {
            comp(C);
            if (pe + 6 < np) C = ldst(pe + 6);
          }
          if (pe + 3 < np) {
            comp(D);
            if (pe + 7 < np) D = ldst(pe + 7);
          }
        }
      }

      // cross-half reduce; hf==0 lanes write BOTH hi and lo
#pragma unroll
      for (int b = 0; b < 8; ++b) {
        float v0 = acc[b][0] + __shfl_xor(acc[b][0], 32);
        float v1 = acc[b][1] + __shfl_xor(acc[b][1], 32);
        float v2 = acc[b][2] + __shfl_xor(acc[b][2], 32);
        float v3 = acc[b][3] + __shfl_xor(acc[b][3], 32);
        if (hf == 0) {
          unsigned int p0 = splitbf(v0), p1 = splitbf(v1), p2 = splitbf(v2), p3 = splitbf(v3);
          u16x4 hh, ll;
          hh[0] = (u16)p0; ll[0] = (u16)(p0 >> 16);
          hh[1] = (u16)p1; ll[1] = (u16)(p1 >> 16);
          hh[2] = (u16)p2; ll[2] = (u16)(p2 >> 16);
          hh[3] = (u16)p3; ll[3] = (u16)(p3 >> 16);
          int idx = nn * ZK + b * TD + q * 4;
          *reinterpret_cast<u16x4*>(zh + idx) = hh;
          *reinterpret_cast<u16x4*>(zl + idx) = ll;
        }
      }
    }
  }
  __syncthreads();

  // ---- phase 2: MFMA GEMM (R2/R6/R8-exact) ----
  const int w = t >> 6, lane = t & 63;
  const int mc = lane & 15, kg = lane >> 4;

  if constexpr (DOUT == 128) {
    f32x4 acc = {0.f, 0.f, 0.f, 0.f};
    {
      const u16* za = zh + mc * ZK + kg * 8;
      const u16* zb = zl + mc * ZK + kg * 8;
      const u16* bha = wth + (size_t)(w * 16 + mc) * TK + kg * 8;
      const u16* bla = wtl + (size_t)(w * 16 + mc) * TK + kg * 8;
#pragma unroll 4
      for (int ks = 0; ks < 32; ++ks) {
        bf16x8 ah  = *(const bf16x8*)(za + 32 * ks);
        bf16x8 alo = *(const bf16x8*)(zb + 32 * ks);
        bf16x8 bh  = *(const bf16x8*)(bha + 32 * ks);
        bf16x8 blo = *(const bf16x8*)(bla + 32 * ks);
        acc = MFMA16(ah, bh, acc);
        acc = MFMA16(alo, bh, acc);
        acc = MFMA16(ah, blo, acc);
      }
      const u16* xa = xh + mc * XK + kg * 8;
      const u16* xb = xl2 + mc * XK + kg * 8;
      const u16* rha = rth + (size_t)(w * 16 + mc) * TD + kg * 8;
      const u16* rla = rtl + (size_t)(w * 16 + mc) * TD + kg * 8;
#pragma unroll
      for (int ks = 0; ks < 4; ++ks) {
        bf16x8 ah  = *(const bf16x8*)(xa + 32 * ks);
        bf16x8 alo = *(const bf16x8*)(xb + 32 * ks);
        bf16x8 bh  = *(const bf16x8*)(rha + 32 * ks);
        bf16x8 blo = *(const bf16x8*)(rla + 32 * ks);
        acc = MFMA16(ah, bh, acc);
        acc = MFMA16(alo, bh, acc);
        acc = MFMA16(ah, blo, acc);
      }
    }
    float bb = bias[w * 16 + mc];
#pragma unroll
    for (int j = 0; j < 4; ++j) {
      int n = n0 + kg * 4 + j;
      if (n < Ntot) {
        float v = acc[j] + bb;
        if (RELU) v = fmaxf(v, 0.f);
        if constexpr (OUTH16) {
          ((u16*)outv)[(size_t)n * 128 + w * 16 + mc] = f2h(v);
        } else {
          ((float*)outv)[(size_t)n * 128 + w * 16 + mc] = v;
        }
      }
    }
  } else {
    // DOUT == 32: 8-way K-split across waves, both col tiles per wave
    f32x4 a0 = {0.f, 0.f, 0.f, 0.f}, a1 = {0.f, 0.f, 0.f, 0.f};
    {
      const u16* za = zh + mc * ZK + kg * 8;
      const u16* zb = zl + mc * ZK + kg * 8;
      const u16* b0h = wth + (size_t)mc * TK + kg * 8;
      const u16* b0l = wtl + (size_t)mc * TK + kg * 8;
      const u16* b1h = wth + (size_t)(16 + mc) * TK + kg * 8;
      const u16* b1l = wtl + (size_t)(16 + mc) * TK + kg * 8;
#pragma unroll
      for (int i = 0; i < 4; ++i) {
        int ks = w * 4 + i;
        bf16x8 ah  = *(const bf16x8*)(za + 32 * ks);
        bf16x8 alo = *(const bf16x8*)(zb + 32 * ks);
        bf16x8 bh0 = *(const bf16x8*)(b0h + 32 * ks);
        bf16x8 bl0 = *(const bf16x8*)(b0l + 32 * ks);
        bf16x8 bh1 = *(const bf16x8*)(b1h + 32 * ks);
        bf16x8 bl1 = *(const bf16x8*)(b1l + 32 * ks);
        a0 = MFMA16(ah, bh0, a0);
        a0 = MFMA16(alo, bh0, a0);
        a0 = MFMA16(ah, bl0, a0);
        a1 = MFMA16(ah, bh1, a1);
        a1 = MFMA16(alo, bh1, a1);
        a1 = MFMA16(ah, bl1, a1);
      }
      if (w < 4) {
        int ks = w;
        bf16x8 ah  = *(const bf16x8*)(xh + mc * XK + kg * 8 + 32 * ks);
        bf16x8 alo = *(const bf16x8*)(xl2 + mc * XK + kg * 8 + 32 * ks);
        bf16x8 bh0 = *(const bf16x8*)(rth + (size_t)mc * TD + kg * 8 + 32 * ks);
        bf16x8 bl0 = *(const bf16x8*)(rtl + (size_t)mc * TD + kg * 8 + 32 * ks);
        bf16x8 bh1 = *(const bf16x8*)(rth + (size_t)(16 + mc) * TD + kg * 8 + 32 * ks);
        bf16x8 bl1 = *(const bf16x8*)(rtl + (size_t)(16 + mc) * TD + kg * 8 + 32 * ks);
        a0 = MFMA16(ah, bh0, a0);
        a0 = MFMA16(alo, bh0, a0);
        a0 = MFMA16(ah, bl0, a0);
        a1 = MFMA16(ah, bh1, a1);
        a1 = MFMA16(alo, bh1, a1);
        a1 = MFMA16(ah, bl1, a1);
      }
    }
    __syncthreads();                       // all z reads done
    float* pc = (float*)smem;              // [8 waves][2 tiles][256] partials
#pragma unroll
    for (int j = 0; j < 4; ++j) {
      pc[(w * 2 + 0) * 256 + (kg * 4 + j) * 16 + mc] = a0[j];
      pc[(w * 2 + 1) * 256 + (kg * 4 + j) * 16 + mc] = a1[j];
    }
    __syncthreads();
    int row = t >> 5, col = t & 31;
    int tile = col >> 4, cc = col & 15;
    float v = 0.f;
#pragma unroll
    for (int ww = 0; ww < 8; ++ww) v += pc[(ww * 2 + tile) * 256 + row * 16 + cc];
    v += bias[col];
    if constexpr (SOFTMAX) {
      float m = v;
      m = fmaxf(m, __shfl_xor(m, 1));
      m = fmaxf(m, __shfl_xor(m, 2));
      m = fmaxf(m, __shfl_xor(m, 4));
      m = fmaxf(m, __shfl_xor(m, 8));
      m = fmaxf(m, __shfl_xor(m, 16));
      float ev = __expf(v - m);
      float s = ev;
      s += __shfl_xor(s, 1); s += __shfl_xor(s, 2); s += __shfl_xor(s, 4);
      s += __shfl_xor(s, 8); s += __shfl_xor(s, 16);
      v = ev / s;
    }
    int n = n0 + row;
    if (n < Ntot) ((float*)outv)[(size_t)n * 32 + col] = v;
  }
}

extern "C" void kernel_launch(void* const* d_in, const int* in_sizes, int n_in,
                              void* d_out, int out_size, void* d_ws, size_t ws_size,
                              hipStream_t stream) {
  const float* x     = (const float*)d_in[0];
  const float* V1    = (const float*)d_in[1];
  const float* a1    = (const float*)d_in[2];
  const float* root1 = (const float*)d_in[3];
  const float* bias1 = (const float*)d_in[4];
  const float* V2    = (const float*)d_in[5];
  const float* a2    = (const float*)d_in[6];
  const float* root2 = (const float*)d_in[7];
  const float* bias2 = (const float*)d_in[8];
  const int*   ei    = (const int*)d_in[9];    // [2, E]
  const int*   et    = (const int*)d_in[10];   // [E]

  const int N = in_sizes[0] / TD;
  const int E = in_sizes[10];
  const int R = 32;

  char* w = (char*)d_ws;
  auto alloc = [&](size_t bytes) {
    char* p = w;
    w += (bytes + 255) & ~(size_t)255;
    return p;
  };
  int*   off    = (int*)alloc((size_t)(N + 1) * 4);
  int*   cursor = (int*)alloc((size_t)N * 4);
  int*   deg    = (int*)alloc((size_t)N * 4);
  int*   cnt2   = (int*)alloc((size_t)R * N * 4);
  int*   packed = (int*)alloc((size_t)E * 4);
  float* invc   = (float*)alloc((size_t)E * 4);
  u16*   xb     = (u16*)alloc((size_t)N * TD * 2);   // fp16 x (messages)
  u16*   hb     = (u16*)alloc((size_t)N * TD * 2);   // fp16 h
  u16*   v1th   = (u16*)alloc((size_t)128 * 1024 * 2);
  u16*   v1tl   = (u16*)alloc((size_t)128 * 1024 * 2);
  u16*   r1th   = (u16*)alloc((size_t)128 * 128 * 2);
  u16*   r1tl   = (u16*)alloc((size_t)128 * 128 * 2);
  u16*   v2th   = (u16*)alloc((size_t)32 * 1024 * 2);
  u16*   v2tl   = (u16*)alloc((size_t)32 * 1024 * 2);
  u16*   r2th   = (u16*)alloc((size_t)32 * 128 * 2);
  u16*   r2tl   = (u16*)alloc((size_t)32 * 128 * 2);

  hipMemsetAsync(deg, 0, (size_t)N * 4, stream);
  hipMemsetAsync(cnt2, 0, (size_t)R * N * 4, stream);

  k_prep<<<512, 256, 0, stream>>>(V1, root1, V2, root2,
                                  v1th, v1tl, r1th, r1tl, v2th, v2tl, r2th, r2tl);
  int n4 = N * TD / 4;
  k_xcast<<<(n4 + 255) / 256, 256, 0, stream>>>(x, xb, n4);

  int egrid = (E + 255) / 256;
  k_hist<<<egrid, 256, 0, stream>>>(ei, et, deg, cnt2, E, N);
  k_scan<<<1, 1024, 0, stream>>>(deg, off, cursor, N, E);
  k_scatter<<<egrid, 256, 0, stream>>>(ei, et, cursor, cnt2, packed, invc, E, N);

  const size_t shmem = (size_t)(2 * TNB * ZK + 2 * TNB * XK) * 2 + 256 * 4 + (size_t)EC * 8;
  (void)hipFuncSetAttribute(reinterpret_cast<const void*>(&k_layer<128, true, false, true, true>),
                            hipFuncAttributeMaxDynamicSharedMemorySize, (int)shmem);
  (void)hipFuncSetAttribute(reinterpret_cast<const void*>(&k_layer<32, false, true, false, false>),
                            hipFuncAttributeMaxDynamicSharedMemorySize, (int)shmem);

  int ngrid = (N + TNB - 1) / TNB;
  k_layer<128, true, false, true, true><<<ngrid, BLK, shmem, stream>>>(
      x, xb, v1th, v1tl, a1, r1th, r1tl, bias1, off, packed, invc, hb, N);
  k_layer<32, false, true, false, false><<<ngrid, BLK, shmem, stream>>>(
      nullptr, hb, v2th, v2tl, a2, r2th, r2tl, bias2, off, packed, invc, d_out, N);
}